// Round 4
// baseline (804.689 us; speedup 1.0000x reference)
//
#include <hip/hip_runtime.h>
#include <hip/hip_bf16.h>
#include <cstdint>
#include <cstddef>

#define F_DIM 512
#define NHEAD 8
#define DD 64
#define NPROT 6144
#define NLIG 3072
#define NACT 9216
#define NTOT 12288

typedef unsigned short u16;
typedef __attribute__((ext_vector_type(8))) short bf8;    // 8 x bf16 (4 VGPR)
typedef __attribute__((ext_vector_type(4))) float f4;
typedef __attribute__((ext_vector_type(16))) float f16f;  // 32x32 MFMA acc
typedef __attribute__((ext_vector_type(2))) unsigned int u32x2;

__device__ __forceinline__ u16 f2bf(float f){
  union { float f; uint32_t u; } v; v.f = f;
  uint32_t r = v.u + 0x7fffu + ((v.u >> 16) & 1u);
  return (u16)(r >> 16);
}

__device__ __forceinline__ f4 mfma16(bf8 a, bf8 b, f4 c){
  return __builtin_amdgcn_mfma_f32_16x16x32_bf16(a, b, c, 0, 0, 0);
}

__device__ __forceinline__ float exp2_fast(float x){
  float r;
  asm volatile("v_exp_f32 %0, %1\n\ts_nop 1" : "=v"(r) : "v"(x));
  return r;
}
__device__ __forceinline__ uint32_t cvtpk(float a, float b){
  uint32_t r;
  asm("v_cvt_pk_bf16_f32 %0, %1, %2" : "=v"(r) : "v"(a), "v"(b));
  return r;
}

// ---------------- conversion kernels ----------------
__global__ void k_cvt(const float* __restrict__ in, u16* __restrict__ out, int n4){
  int i = blockIdx.x * blockDim.x + threadIdx.x;
  if (i >= n4) return;
  float4 v = ((const float4*)in)[i];
  union { u16 u[4]; uint64_t q; } pk;
  pk.u[0]=f2bf(v.x); pk.u[1]=f2bf(v.y); pk.u[2]=f2bf(v.z); pk.u[3]=f2bf(v.w);
  ((uint64_t*)out)[i] = pk.q;
}

// tiled transpose: out[z][c][r] = bf16(in[z][r][c]); R,C multiples of 64
__global__ __launch_bounds__(256) void k_cvtT64(const float* __restrict__ in,
                                                u16* __restrict__ out, int R, int C){
  __shared__ u16 T[64][65];
  int64_t base = (int64_t)blockIdx.z * R * C;
  int cb = blockIdx.x*64, rb = blockIdx.y*64;
  #pragma unroll
  for (int i=0;i<16;i++){
    int idx = i*256 + threadIdx.x;
    int r = idx>>6, c = idx&63;
    T[r][c] = f2bf(in[base + (int64_t)(rb+r)*C + cb + c]);
  }
  __syncthreads();
  #pragma unroll
  for (int i=0;i<16;i++){
    int idx = i*256 + threadIdx.x;
    int c = idx>>6, r = idx&63;
    out[base + (int64_t)(cb+c)*R + rb + r] = T[r][c];
  }
}

// ---------------- per-head projections: pf/lf (+ transposed copies) ----------------
__global__ __launch_bounds__(256) void k_proj(const u16* __restrict__ hb,
    const u16* __restrict__ WpT, const u16* __restrict__ WlT,
    u16* __restrict__ pf, u16* __restrict__ pfT,
    u16* __restrict__ lfb, u16* __restrict__ lfT){
  int pass = blockIdx.z;
  if (pass == 1 && blockIdx.x >= NLIG/64) return;
  int M = pass ? NLIG : NPROT;
  const u16* A  = hb + (pass ? (size_t)NPROT*F_DIM : 0);
  const u16* BT = pass ? WlT : WpT;
  u16* P  = pass ? lfb : pf;
  u16* PT = pass ? lfT : pfT;
  int h = blockIdx.y;
  int w = threadIdx.x >> 6, lane = threadIdx.x & 63;
  int lr = lane & 15, lkg = lane >> 4, lk = lkg * 8;
  int rb = blockIdx.x * 64;
  const u16* Ap = A + (size_t)(rb + w*16 + lr) * F_DIM + lk;
  const u16* Bp = BT + (size_t)h * DD * F_DIM + (size_t)lr * F_DIM + lk;
  f4 acc[4] = {};
  for (int k = 0; k < F_DIM; k += 32){
    bf8 a = *(const bf8*)(Ap + k);
    #pragma unroll
    for (int cf = 0; cf < 4; cf++){
      bf8 b = *(const bf8*)(Bp + (size_t)cf*16*F_DIM + k);
      acc[cf] = mfma16(a, b, acc[cf]);
    }
  }
  __shared__ u16 T[64*72];
  #pragma unroll
  for (int cf = 0; cf < 4; cf++){
    int d = cf*16 + lr;
    #pragma unroll
    for (int r = 0; r < 4; r++){
      u16 v = f2bf(acc[cf][r]);
      int rl = w*16 + lkg*4 + r;
      P[(size_t)h*M*DD + (size_t)(rb+rl)*DD + d] = v;
      T[rl*72 + d] = v;
    }
  }
  __syncthreads();
  int d = threadIdx.x >> 2, j = threadIdx.x & 3;
  union { u16 u[16]; bf8 v[2]; } pk;
  #pragma unroll
  for (int uu = 0; uu < 16; uu++) pk.u[uu] = T[(j*16+uu)*72 + d];
  bf8* dst = (bf8*)(PT + ((size_t)h*DD + d)*M + rb + j*16);
  dst[0] = pk.v[0]; dst[1] = pk.v[1];
}

// ---------------- gates: sigmoid(h @ gw + gb) ----------------
__global__ __launch_bounds__(256) void k_gate(const u16* __restrict__ hb,
    const u16* __restrict__ pgT, const u16* __restrict__ lgT,
    const float* __restrict__ pgb, const float* __restrict__ lgb,
    float* __restrict__ pgate, float* __restrict__ lgate){
  int pass = blockIdx.z;
  if (pass == 1 && blockIdx.x >= NLIG/64) return;
  const u16* A  = hb + (pass ? (size_t)NPROT*F_DIM : 0);
  const u16* BT = pass ? lgT : pgT;
  const float* gb = pass ? lgb : pgb;
  float* outp = pass ? lgate : pgate;
  int w = threadIdx.x>>6, lane = threadIdx.x&63, lr = lane&15, lkg = lane>>4, lk = lkg*8;
  int rb = blockIdx.x*64;
  const u16* Ap = A + (size_t)(rb + w*16 + lr)*F_DIM + lk;
  const u16* Bp = BT + (size_t)lr*F_DIM + lk;
  f4 acc[4] = {};
  for (int k=0;k<F_DIM;k+=32){
    bf8 a = *(const bf8*)(Ap+k);
    #pragma unroll
    for (int cf=0;cf<4;cf++){
      bf8 b = *(const bf8*)(Bp + (size_t)cf*16*F_DIM + k);
      acc[cf]=mfma16(a,b,acc[cf]);
    }
  }
  int r0 = rb + w*16 + lkg*4;
  #pragma unroll
  for (int cf=0;cf<4;cf++){
    int d = cf*16+lr; float bb = gb[d];
    #pragma unroll
    for (int r=0;r<4;r++){
      float z = acc[cf][r] + bb;
      outp[(size_t)(r0+r)*DD + d] = 1.f/(1.f + __expf(-z));
    }
  }
}

// ---------------- M_h = U_w[h] @ fl_w_h  -> stored transposed [fo][h*64+d] ----------------
__global__ __launch_bounds__(256) void k_mw(const u16* __restrict__ UpWb, const u16* __restrict__ UlWb,
    const u16* __restrict__ flT, u16* __restrict__ MpT, u16* __restrict__ MlT){
  const u16* A = blockIdx.z ? UlWb : UpWb;
  u16* O = blockIdx.z ? MlT : MpT;
  int h = blockIdx.y;
  int fobase = blockIdx.x * 64;
  int w = threadIdx.x>>6, lane = threadIdx.x&63, lr = lane&15, lkg = lane>>4, lk = lkg*8;
  const u16* Ap = A + (size_t)h*DD*F_DIM + (size_t)(w*16+lr)*F_DIM + lk;
  const u16* Bp = flT + (size_t)(fobase+lr)*(NHEAD*F_DIM) + (size_t)h*F_DIM + lk;
  f4 acc[4] = {};
  for (int k=0;k<F_DIM;k+=32){
    bf8 a = *(const bf8*)(Ap+k);
    #pragma unroll
    for (int cf=0;cf<4;cf++){
      bf8 b = *(const bf8*)(Bp + (size_t)cf*16*(NHEAD*F_DIM) + k);
      acc[cf]=mfma16(a,b,acc[cf]);
    }
  }
  int d0 = w*16 + lkg*4;
  #pragma unroll
  for (int cf=0;cf<4;cf++){
    int fo = fobase + cf*16 + lr;
    #pragma unroll
    for (int r=0;r<4;r++)
      O[(size_t)fo*F_DIM + h*DD + d0 + r] = f2bf(acc[cf][r]);
  }
}

// ---------------- cp/cl = fl_b + Ub_cat @ fl_w ----------------
__global__ void k_cinit(const float* __restrict__ flb, float* __restrict__ cp, float* __restrict__ cl){
  int i = blockIdx.x*blockDim.x + threadIdx.x;
  if (i < F_DIM){ cp[i] = flb[i]; cl[i] = flb[i]; }
}
__global__ void k_cacc(const float* __restrict__ flw, const float* __restrict__ Upb,
    const float* __restrict__ Ulb, float* __restrict__ cp, float* __restrict__ cl){
  const float* bias = blockIdx.z ? Ulb : Upb;
  float* o = blockIdx.z ? cl : cp;
  int fo = blockIdx.y*256 + threadIdx.x;
  int r0 = blockIdx.x*128;
  float acc = 0.f;
  #pragma unroll 4
  for (int r = r0; r < r0+128; r++) acc += bias[r] * flw[(size_t)r*F_DIM + fo];
  atomicAdd(o + fo, acc);
}

// ---------------- chunked co-attention, 32x32 swapped-MFMA, LDS-free ----------
// grid.x = 1536: pass0 = 48 qtiles(128) x 2 chunks(1536) x 8 heads = 768
//                pass1 = 24 qtiles(128) x 4 chunks(1536) x 8 heads = 768
// Per wave: 32 q rows. S^T = mfma32(K, Q) -> scores lane-local per q.
// P->bf16 B-frags via cvt_pk + permlane32_swap (no LDS, no shuffles for den).
__global__ __launch_bounds__(256, 2) void k_attn(
    const u16* __restrict__ pf, const u16* __restrict__ lfb,
    const u16* __restrict__ pfT, const u16* __restrict__ lfT,
    float* __restrict__ pnum, float* __restrict__ pden,
    float* __restrict__ lnum, float* __restrict__ lden){
  int bid = blockIdx.x;
  int pass = (bid >= 768);
  int NQ, NK, qt, chunk, h;
  const u16 *Q, *Kt, *Vt; float *num, *den;
  if (!pass){
    qt = bid >> 4; int rem = bid & 15; chunk = rem >> 3; h = rem & 7;
    NQ = NPROT; NK = NLIG; Q = pf; Kt = lfb; Vt = lfT; num = pnum; den = pden;
  } else {
    int l = bid - 768; qt = l >> 5; int rem = l & 31; chunk = rem >> 3; h = rem & 7;
    NQ = NLIG; NK = NPROT; Q = lfb; Kt = pf; Vt = pfT; num = lnum; den = lden;
  }
  int wv = threadIdx.x>>6, lane = threadIdx.x&63;
  int ql = lane&31, hi = lane>>5;
  int qg = qt*128 + wv*32 + ql;
  const u16* Qh = Q + (size_t)h*NQ*DD;
  const u16* Kh = Kt + (size_t)h*NK*DD;
  const u16* Vh = Vt + (size_t)h*DD*NK;
  const float SC = 0.125f * 1.44269504088896f;   // log2(e)/sqrt(D)

  // Q as B-operand: lane(col=q, k=hi*8+j), 4 slices of k16 over D=64
  bf8 qf[4];
  #pragma unroll
  for (int kk=0;kk<4;kk++)
    qf[kk] = *(const bf8*)(Qh + (size_t)qg*DD + kk*16 + hi*8);

  f16f o0 = {}, o1 = {};
  float dsum = 0.f;
  int kv0 = chunk*1536;
  const u16* Kp  = Kh + (size_t)(kv0 + ql)*DD + hi*8;
  const u16* Vp0 = Vh + (size_t)ql*NK + kv0 + hi*8;
  const u16* Vp1 = Vh + (size_t)(32+ql)*NK + kv0 + hi*8;

  for (int t=0; t<48; t++){
    // S^T[kv][q]: A = K rows(kv), B = Q^T
    f16f s = {};
    #pragma unroll
    for (int kk=0;kk<4;kk++){
      bf8 kf = *(const bf8*)(Kp + kk*16);
      s = __builtin_amdgcn_mfma_f32_32x32x16_bf16(kf, qf[kk], s, 0, 0, 0);
    }
    // lane(q,hi) holds S^T[kvl=(r&3)+8*(r>>2)+4*hi][q]
    float e[16];
    #pragma unroll
    for (int r=0;r<16;r++){ e[r] = exp2_fast(s[r]*SC); dsum += e[r]; }
    // B-frags for PV: lane(q,hi) needs P[kv = base + hi*8 + j][q]
    union { uint32_t u[4]; bf8 v; } B0, B1;
    {
      u32x2 p;
      p = __builtin_amdgcn_permlane32_swap(cvtpk(e[0],e[1]),   cvtpk(e[4],e[5]),   false, false);
      B0.u[0]=p[0]; B0.u[2]=p[1];
      p = __builtin_amdgcn_permlane32_swap(cvtpk(e[2],e[3]),   cvtpk(e[6],e[7]),   false, false);
      B0.u[1]=p[0]; B0.u[3]=p[1];
      p = __builtin_amdgcn_permlane32_swap(cvtpk(e[8],e[9]),   cvtpk(e[12],e[13]), false, false);
      B1.u[0]=p[0]; B1.u[2]=p[1];
      p = __builtin_amdgcn_permlane32_swap(cvtpk(e[10],e[11]), cvtpk(e[14],e[15]), false, false);
      B1.u[1]=p[0]; B1.u[3]=p[1];
    }
    // O^T[d][q] += V^T[d][kv] * P[kv][q]
    bf8 v00 = *(const bf8*)(Vp0);
    bf8 v01 = *(const bf8*)(Vp0 + 16);
    bf8 v10 = *(const bf8*)(Vp1);
    bf8 v11 = *(const bf8*)(Vp1 + 16);
    o0 = __builtin_amdgcn_mfma_f32_32x32x16_bf16(v00, B0.v, o0, 0, 0, 0);
    o0 = __builtin_amdgcn_mfma_f32_32x32x16_bf16(v01, B1.v, o0, 0, 0, 0);
    o1 = __builtin_amdgcn_mfma_f32_32x32x16_bf16(v10, B0.v, o1, 0, 0, 0);
    o1 = __builtin_amdgcn_mfma_f32_32x32x16_bf16(v11, B1.v, o1, 0, 0, 0);
    Kp += 32*DD; Vp0 += 32; Vp1 += 32;
  }

  // den: each lane's dsum covers its 16 kv's per tile; union over hi = all kv
  atomicAdd(&den[(size_t)h*NQ + qg], dsum);
  float* np = num + ((size_t)h*NQ + qg)*DD;
  #pragma unroll
  for (int r=0;r<16;r++){
    int d = (r&3) + 8*(r>>2) + 4*hi;
    atomicAdd(np + d,      o0[r]);
    atomicAdd(np + 32 + d, o1[r]);
  }
}

// ---------------- epilogue: gate * num/den -> LN -> fb -> sigmoid -> pc2/lc2 ----------
__global__ __launch_bounds__(256) void k_post(
    const float* __restrict__ pnum, const float* __restrict__ pden,
    const float* __restrict__ lnum, const float* __restrict__ lden,
    const float* __restrict__ pgate, const float* __restrict__ lgate,
    const float* __restrict__ lnw, const float* __restrict__ lnb,
    const u16* __restrict__ fbT, const float* __restrict__ fbb,
    u16* __restrict__ pc2, u16* __restrict__ lc2){
  int t = blockIdx.x;
  int pass = (t >= NPROT/64);
  int h = blockIdx.y;
  int NQ = pass ? NLIG : NPROT;
  const float* num = pass ? lnum : pnum;
  const float* den = pass ? lden : pden;
  const float* gate = pass ? lgate : pgate;
  u16* oc = pass ? lc2 : pc2;
  int qbase = (pass ? t - NPROT/64 : t) * 64;

  __shared__ u16 Pl[64*72];
  int w = threadIdx.x>>6, lane = threadIdx.x&63;
  int lr = lane&15, lkg = lane>>4, lk = lkg*8;
  u16* Pw = Pl + (w*16)*72;
  int orow0 = qbase + w*16 + lkg*4;

  float rd[4];
  #pragma unroll
  for (int r=0;r<4;r++) rd[r] = 1.f / den[(size_t)h*NQ + orow0 + r];

  float v[4][4];
  #pragma unroll
  for (int cf=0;cf<4;cf++){
    int d = cf*16+lr;
    #pragma unroll
    for (int r=0;r<4;r++)
      v[cf][r] = num[((size_t)h*NQ + orow0 + r)*DD + d] * rd[r]
               * gate[(size_t)(orow0+r)*DD + d];
  }
  float m1[4], m2[4];
  #pragma unroll
  for (int r=0;r<4;r++){
    float s1 = v[0][r]+v[1][r]+v[2][r]+v[3][r];
    float s2 = v[0][r]*v[0][r]+v[1][r]*v[1][r]+v[2][r]*v[2][r]+v[3][r]*v[3][r];
    s1 += __shfl_xor(s1,1,64); s2 += __shfl_xor(s2,1,64);
    s1 += __shfl_xor(s1,2,64); s2 += __shfl_xor(s2,2,64);
    s1 += __shfl_xor(s1,4,64); s2 += __shfl_xor(s2,4,64);
    s1 += __shfl_xor(s1,8,64); s2 += __shfl_xor(s2,8,64);
    float mu = s1 * (1.f/64.f);
    float var = s2 * (1.f/64.f) - mu*mu;
    if (var < 0.f) var = 0.f;
    m1[r] = mu; m2[r] = rsqrtf(var + 1e-5f);
  }
  #pragma unroll
  for (int cf=0;cf<4;cf++){
    int d = cf*16+lr;
    float lw = lnw[d], lb = lnb[d];
    #pragma unroll
    for (int r=0;r<4;r++){
      float n = (v[cf][r]-m1[r])*m2[r]*lw + lb;
      Pw[(lkg*4+r)*72 + d] = f2bf(n);
    }
  }
  f4 z4[4] = {};
  #pragma unroll
  for (int kc=0;kc<2;kc++){
    bf8 pa = *(const bf8*)(Pw + lr*72 + kc*32 + lk);
    #pragma unroll
    for (int cf=0;cf<4;cf++){
      bf8 b = *(const bf8*)(fbT + (size_t)(cf*16+lr)*DD + kc*32 + lk);
      z4[cf] = mfma16(pa, b, z4[cf]);
    }
  }
  #pragma unroll
  for (int cf=0;cf<4;cf++){
    int d = cf*16+lr;
    float bb = fbb[d];
    #pragma unroll
    for (int r=0;r<4;r++){
      float sg = 1.f/(1.f + __expf(-(z4[cf][r] + bb)));
      oc[(size_t)(orow0+r)*F_DIM + h*DD + d] = f2bf(sg);
    }
  }
}

// ---------------- final: out = h (+ cat @ M^T + c for active rows) ----------------
__global__ __launch_bounds__(256) void k_final(const float* __restrict__ hsrc,
    const u16* __restrict__ pc2, const u16* __restrict__ lc2,
    const u16* __restrict__ MpT, const u16* __restrict__ MlT,
    const float* __restrict__ cp, const float* __restrict__ cl,
    float* __restrict__ out){
  int R = blockIdx.x*64;
  int cbase = blockIdx.y*64;
  int tid = threadIdx.x;
  if (R >= NACT){
    int r = tid>>2, s0 = tid&3;
    const float4* hp4 = (const float4*)(hsrc + (size_t)(R+r)*F_DIM + cbase);
    float4* op4 = (float4*)(out + (size_t)(R+r)*F_DIM + cbase);
    #pragma unroll
    for (int s=0;s<4;s++) op4[s0 + s*4] = hp4[s0 + s*4];
    return;
  }
  bool isP = (R < NPROT);
  const u16* A = isP ? (pc2 + (size_t)R*F_DIM) : (lc2 + (size_t)(R-NPROT)*F_DIM);
  const u16* B = isP ? MpT : MlT;
  const float* cv = isP ? cp : cl;
  int w = tid>>6, lane = tid&63, lr = lane&15, lkg = lane>>4, lk = lkg*8;
  const u16* Ap = A + (size_t)(w*16+lr)*F_DIM + lk;
  const u16* Bp = B + (size_t)(cbase+lr)*F_DIM + lk;
  f4 acc[4] = {};
  for (int k=0;k<F_DIM;k+=32){
    bf8 a = *(const bf8*)(Ap+k);
    #pragma unroll
    for (int cf=0;cf<4;cf++){
      bf8 b = *(const bf8*)(Bp + (size_t)cf*16*F_DIM + k);
      acc[cf]=mfma16(a,b,acc[cf]);
    }
  }
  int row0 = R + w*16 + lkg*4;
  #pragma unroll
  for (int cf=0;cf<4;cf++){
    int c = cbase + cf*16 + lr;
    float cc = cv[c];
    #pragma unroll
    for (int r=0;r<4;r++)
      out[(size_t)(row0+r)*F_DIM + c] = acc[cf][r] + cc + hsrc[(size_t)(row0+r)*F_DIM + c];
  }
}

extern "C" void kernel_launch(void* const* d_in, const int* in_sizes, int n_in,
                              void* d_out, int out_size, void* d_ws, size_t ws_size,
                              hipStream_t stream){
  (void)in_sizes; (void)n_in; (void)out_size; (void)ws_size;
  const float* h    = (const float*)d_in[0];
  const float* Wp   = (const float*)d_in[3];
  const float* Wl   = (const float*)d_in[4];
  const float* Upw  = (const float*)d_in[5];
  const float* Upb  = (const float*)d_in[6];
  const float* Ulw  = (const float*)d_in[7];
  const float* Ulb  = (const float*)d_in[8];
  const float* lnw  = (const float*)d_in[9];
  const float* lnb  = (const float*)d_in[10];
  const float* pgw  = (const float*)d_in[11];
  const float* pgb  = (const float*)d_in[12];
  const float* lgw  = (const float*)d_in[13];
  const float* lgb  = (const float*)d_in[14];
  const float* fbw  = (const float*)d_in[15];
  const float* fbb  = (const float*)d_in[16];
  const float* flw  = (const float*)d_in[17];
  const float* flb  = (const float*)d_in[18];
  float* out = (float*)d_out;

  char* wsp = (char*)d_ws;
  size_t off = 0;
  auto alloc = [&](size_t b)->char* {
    char* p = wsp + off; off = (off + b + 255) & ~(size_t)255; return p;
  };
  u16* hb    = (u16*)alloc((size_t)NACT*F_DIM*2);
  u16* WpT   = (u16*)alloc((size_t)NHEAD*DD*F_DIM*2);
  u16* WlT   = (u16*)alloc((size_t)NHEAD*DD*F_DIM*2);
  u16* pgT   = (u16*)alloc((size_t)DD*F_DIM*2);
  u16* lgT   = (u16*)alloc((size_t)DD*F_DIM*2);
  u16* fbT   = (u16*)alloc((size_t)DD*DD*2);
  u16* UpWb  = (u16*)alloc((size_t)NHEAD*DD*F_DIM*2);
  u16* UlWb  = (u16*)alloc((size_t)NHEAD*DD*F_DIM*2);
  u16* flT   = (u16*)alloc((size_t)F_DIM*NHEAD*F_DIM*2);
  u16* pf    = (u16*)alloc((size_t)NHEAD*NPROT*DD*2);
  u16* pfT   = (u16*)alloc((size_t)NHEAD*DD*NPROT*2);
  u16* lfb   = (u16*)alloc((size_t)NHEAD*NLIG*DD*2);
  u16* lfT   = (u16*)alloc((size_t)NHEAD*DD*NLIG*2);
  float* pgate = (float*)alloc((size_t)NPROT*DD*4);
  float* lgate = (float*)alloc((size_t)NLIG*DD*4);
  u16* pc2   = (u16*)alloc((size_t)NPROT*F_DIM*2);
  u16* lc2   = (u16*)alloc((size_t)NLIG*F_DIM*2);
  u16* MpT   = (u16*)alloc((size_t)F_DIM*F_DIM*2);
  u16* MlT   = (u16*)alloc((size_t)F_DIM*F_DIM*2);
  float* cp  = (float*)alloc(F_DIM*4);
  float* cl  = (float*)alloc(F_DIM*4);
  // attention accumulation buffers (zeroed each call)
  size_t n_pnum = (size_t)NHEAD*NPROT*DD, n_lnum = (size_t)NHEAD*NLIG*DD;
  size_t n_pden = (size_t)NHEAD*NPROT,     n_lden = (size_t)NHEAD*NLIG;
  size_t accN = n_pnum + n_lnum + n_pden + n_lden;
  float* accbuf = (float*)alloc(accN*4);
  float* pnum = accbuf;
  float* lnum = pnum + n_pnum;
  float* pden = lnum + n_lnum;
  float* lden = pden + n_pden;

  hipMemsetAsync(accbuf, 0, accN*4, stream);

  // prep: bf16 conversions / transposes
  k_cvt<<<dim3((NACT*F_DIM/4 + 255)/256), 256, 0, stream>>>(h, hb, NACT*F_DIM/4);
  k_cvt<<<dim3((NHEAD*DD*F_DIM/4 + 255)/256), 256, 0, stream>>>(Upw, UpWb, NHEAD*DD*F_DIM/4);
  k_cvt<<<dim3((NHEAD*DD*F_DIM/4 + 255)/256), 256, 0, stream>>>(Ulw, UlWb, NHEAD*DD*F_DIM/4);
  k_cvtT64<<<dim3(1, 8, NHEAD), 256, 0, stream>>>(Wp, WpT, F_DIM, DD);
  k_cvtT64<<<dim3(1, 8, NHEAD), 256, 0, stream>>>(Wl, WlT, F_DIM, DD);
  k_cvtT64<<<dim3(1, 8, 1), 256, 0, stream>>>(pgw, pgT, F_DIM, DD);
  k_cvtT64<<<dim3(1, 8, 1), 256, 0, stream>>>(lgw, lgT, F_DIM, DD);
  k_cvtT64<<<dim3(1, 1, 1), 256, 0, stream>>>(fbw, fbT, DD, DD);
  k_cvtT64<<<dim3(8, 64, 1), 256, 0, stream>>>(flw, flT, NHEAD*F_DIM, F_DIM);

  // projections, gates, folded output matrices
  k_proj<<<dim3(NPROT/64, NHEAD, 2), 256, 0, stream>>>(hb, WpT, WlT, pf, pfT, lfb, lfT);
  k_gate<<<dim3(NPROT/64, 1, 2), 256, 0, stream>>>(hb, pgT, lgT, pgb, lgb, pgate, lgate);
  k_mw<<<dim3(F_DIM/64, NHEAD, 2), 256, 0, stream>>>(UpWb, UlWb, flT, MpT, MlT);
  k_cinit<<<dim3(2), 256, 0, stream>>>(flb, cp, cl);
  k_cacc<<<dim3(32, 2, 2), 256, 0, stream>>>(flw, Upb, Ulb, cp, cl);

  // chunked co-attention: uniform 1536 blocks, LDS-free in-register softmax
  k_attn<<<dim3(1536), 256, 0, stream>>>(pf, lfb, pfT, lfT, pnum, pden, lnum, lden);
  // epilogue
  k_post<<<dim3(NPROT/64 + NLIG/64, NHEAD), 256, 0, stream>>>(
      pnum, pden, lnum, lden, pgate, lgate, lnw, lnb, fbT, fbb, pc2, lc2);
  // final projection + residual + passthrough
  k_final<<<dim3(NTOT/64, F_DIM/64), 256, 0, stream>>>(h, pc2, lc2, MpT, MlT, cp, cl, out);
}

// Round 5
// 542.438 us; speedup vs baseline: 1.4835x; 1.4835x over previous
//
#include <hip/hip_runtime.h>
#include <hip/hip_bf16.h>
#include <cstdint>
#include <cstddef>

#define F_DIM 512
#define NHEAD 8
#define DD 64
#define NPROT 6144
#define NLIG 3072
#define NACT 9216
#define NTOT 12288

typedef unsigned short u16;
typedef __attribute__((ext_vector_type(8))) short bf8;    // 8 x bf16 (4 VGPR)
typedef __attribute__((ext_vector_type(4))) float f4;
typedef __attribute__((ext_vector_type(16))) float f16f;  // 32x32 MFMA acc
typedef __attribute__((ext_vector_type(2))) unsigned int u32x2;

__device__ __forceinline__ u16 f2bf(float f){
  union { float f; uint32_t u; } v; v.f = f;
  uint32_t r = v.u + 0x7fffu + ((v.u >> 16) & 1u);
  return (u16)(r >> 16);
}
__device__ __forceinline__ float bf2f(u16 s){
  union { uint32_t u; float f; } v; v.u = ((uint32_t)s) << 16; return v.f;
}

__device__ __forceinline__ f4 mfma16(bf8 a, bf8 b, f4 c){
  return __builtin_amdgcn_mfma_f32_16x16x32_bf16(a, b, c, 0, 0, 0);
}

__device__ __forceinline__ float exp2_fast(float x){
  float r;
  asm("v_exp_f32 %0, %1\n\ts_nop 1" : "=v"(r) : "v"(x));
  return r;
}
__device__ __forceinline__ uint32_t cvtpk(float a, float b){
  uint32_t r;
  asm("v_cvt_pk_bf16_f32 %0, %1, %2" : "=v"(r) : "v"(a), "v"(b));
  return r;
}

// ---------------- conversion kernels ----------------
__global__ void k_cvt(const float* __restrict__ in, u16* __restrict__ out, int n4){
  int i = blockIdx.x * blockDim.x + threadIdx.x;
  if (i >= n4) return;
  float4 v = ((const float4*)in)[i];
  union { u16 u[4]; uint64_t q; } pk;
  pk.u[0]=f2bf(v.x); pk.u[1]=f2bf(v.y); pk.u[2]=f2bf(v.z); pk.u[3]=f2bf(v.w);
  ((uint64_t*)out)[i] = pk.q;
}

// tiled transpose: out[z][c][r] = bf16(in[z][r][c]); R,C multiples of 64
__global__ __launch_bounds__(256) void k_cvtT64(const float* __restrict__ in,
                                                u16* __restrict__ out, int R, int C){
  __shared__ u16 T[64][65];
  int64_t base = (int64_t)blockIdx.z * R * C;
  int cb = blockIdx.x*64, rb = blockIdx.y*64;
  #pragma unroll
  for (int i=0;i<16;i++){
    int idx = i*256 + threadIdx.x;
    int r = idx>>6, c = idx&63;
    T[r][c] = f2bf(in[base + (int64_t)(rb+r)*C + cb + c]);
  }
  __syncthreads();
  #pragma unroll
  for (int i=0;i<16;i++){
    int idx = i*256 + threadIdx.x;
    int c = idx>>6, r = idx&63;
    out[base + (int64_t)(cb+c)*R + rb + r] = T[r][c];
  }
}

// ---------------- per-head projections: pf/lf (+ transposed copies) ----------------
__global__ __launch_bounds__(256) void k_proj(const u16* __restrict__ hb,
    const u16* __restrict__ WpT, const u16* __restrict__ WlT,
    u16* __restrict__ pf, u16* __restrict__ pfT,
    u16* __restrict__ lfb, u16* __restrict__ lfT){
  int pass = blockIdx.z;
  if (pass == 1 && blockIdx.x >= NLIG/64) return;
  int M = pass ? NLIG : NPROT;
  const u16* A  = hb + (pass ? (size_t)NPROT*F_DIM : 0);
  const u16* BT = pass ? WlT : WpT;
  u16* P  = pass ? lfb : pf;
  u16* PT = pass ? lfT : pfT;
  int h = blockIdx.y;
  int w = threadIdx.x >> 6, lane = threadIdx.x & 63;
  int lr = lane & 15, lkg = lane >> 4, lk = lkg * 8;
  int rb = blockIdx.x * 64;
  const u16* Ap = A + (size_t)(rb + w*16 + lr) * F_DIM + lk;
  const u16* Bp = BT + (size_t)h * DD * F_DIM + (size_t)lr * F_DIM + lk;
  f4 acc[4] = {};
  for (int k = 0; k < F_DIM; k += 32){
    bf8 a = *(const bf8*)(Ap + k);
    #pragma unroll
    for (int cf = 0; cf < 4; cf++){
      bf8 b = *(const bf8*)(Bp + (size_t)cf*16*F_DIM + k);
      acc[cf] = mfma16(a, b, acc[cf]);
    }
  }
  __shared__ u16 T[64*72];
  #pragma unroll
  for (int cf = 0; cf < 4; cf++){
    int d = cf*16 + lr;
    #pragma unroll
    for (int r = 0; r < 4; r++){
      u16 v = f2bf(acc[cf][r]);
      int rl = w*16 + lkg*4 + r;
      P[(size_t)h*M*DD + (size_t)(rb+rl)*DD + d] = v;
      T[rl*72 + d] = v;
    }
  }
  __syncthreads();
  int d = threadIdx.x >> 2, j = threadIdx.x & 3;
  union { u16 u[16]; bf8 v[2]; } pk;
  #pragma unroll
  for (int uu = 0; uu < 16; uu++) pk.u[uu] = T[(j*16+uu)*72 + d];
  bf8* dst = (bf8*)(PT + ((size_t)h*DD + d)*M + rb + j*16);
  dst[0] = pk.v[0]; dst[1] = pk.v[1];
}

// ---------------- gates: sigmoid(h @ gw + gb) ----------------
__global__ __launch_bounds__(256) void k_gate(const u16* __restrict__ hb,
    const u16* __restrict__ pgT, const u16* __restrict__ lgT,
    const float* __restrict__ pgb, const float* __restrict__ lgb,
    float* __restrict__ pgate, float* __restrict__ lgate){
  int pass = blockIdx.z;
  if (pass == 1 && blockIdx.x >= NLIG/64) return;
  const u16* A  = hb + (pass ? (size_t)NPROT*F_DIM : 0);
  const u16* BT = pass ? lgT : pgT;
  const float* gb = pass ? lgb : pgb;
  float* outp = pass ? lgate : pgate;
  int w = threadIdx.x>>6, lane = threadIdx.x&63, lr = lane&15, lkg = lane>>4, lk = lkg*8;
  int rb = blockIdx.x*64;
  const u16* Ap = A + (size_t)(rb + w*16 + lr)*F_DIM + lk;
  const u16* Bp = BT + (size_t)lr*F_DIM + lk;
  f4 acc[4] = {};
  for (int k=0;k<F_DIM;k+=32){
    bf8 a = *(const bf8*)(Ap+k);
    #pragma unroll
    for (int cf=0;cf<4;cf++){
      bf8 b = *(const bf8*)(Bp + (size_t)cf*16*F_DIM + k);
      acc[cf]=mfma16(a,b,acc[cf]);
    }
  }
  int r0 = rb + w*16 + lkg*4;
  #pragma unroll
  for (int cf=0;cf<4;cf++){
    int d = cf*16+lr; float bb = gb[d];
    #pragma unroll
    for (int r=0;r<4;r++){
      float z = acc[cf][r] + bb;
      outp[(size_t)(r0+r)*DD + d] = 1.f/(1.f + __expf(-z));
    }
  }
}

// ---------------- M_h = U_w[h] @ fl_w_h  -> stored transposed [fo][h*64+d] ----------------
__global__ __launch_bounds__(256) void k_mw(const u16* __restrict__ UpWb, const u16* __restrict__ UlWb,
    const u16* __restrict__ flT, u16* __restrict__ MpT, u16* __restrict__ MlT){
  const u16* A = blockIdx.z ? UlWb : UpWb;
  u16* O = blockIdx.z ? MlT : MpT;
  int h = blockIdx.y;
  int fobase = blockIdx.x * 64;
  int w = threadIdx.x>>6, lane = threadIdx.x&63, lr = lane&15, lkg = lane>>4, lk = lkg*8;
  const u16* Ap = A + (size_t)h*DD*F_DIM + (size_t)(w*16+lr)*F_DIM + lk;
  const u16* Bp = flT + (size_t)(fobase+lr)*(NHEAD*F_DIM) + (size_t)h*F_DIM + lk;
  f4 acc[4] = {};
  for (int k=0;k<F_DIM;k+=32){
    bf8 a = *(const bf8*)(Ap+k);
    #pragma unroll
    for (int cf=0;cf<4;cf++){
      bf8 b = *(const bf8*)(Bp + (size_t)cf*16*(NHEAD*F_DIM) + k);
      acc[cf]=mfma16(a,b,acc[cf]);
    }
  }
  int d0 = w*16 + lkg*4;
  #pragma unroll
  for (int cf=0;cf<4;cf++){
    int fo = fobase + cf*16 + lr;
    #pragma unroll
    for (int r=0;r<4;r++)
      O[(size_t)fo*F_DIM + h*DD + d0 + r] = f2bf(acc[cf][r]);
  }
}

// ---------------- cp/cl = fl_b + Ub_cat @ fl_w ----------------
__global__ void k_cinit(const float* __restrict__ flb, float* __restrict__ cp, float* __restrict__ cl){
  int i = blockIdx.x*blockDim.x + threadIdx.x;
  if (i < F_DIM){ cp[i] = flb[i]; cl[i] = flb[i]; }
}
__global__ void k_cacc(const float* __restrict__ flw, const float* __restrict__ Upb,
    const float* __restrict__ Ulb, float* __restrict__ cp, float* __restrict__ cl){
  const float* bias = blockIdx.z ? Ulb : Upb;
  float* o = blockIdx.z ? cl : cp;
  int fo = blockIdx.y*256 + threadIdx.x;
  int r0 = blockIdx.x*128;
  float acc = 0.f;
  #pragma unroll 4
  for (int r = r0; r < r0+128; r++) acc += bias[r] * flw[(size_t)r*F_DIM + fo];
  atomicAdd(o + fo, acc);
}

// ---------------- co-attention, 32x32 swapped-MFMA, block-owned output ----------
// grid.x = 1152: bid<384 -> ligand-query (heavy, NK=6144): 48 qtiles x 8 heads
//                bid>=384 -> protein-query: 96 qtiles x 8 heads
// Block = 64 q rows, 4 waves = 2 q-subtiles x 2 kv-halves.
// kv-half-1 waves pass partial O/den via LDS; kv-half-0 waves combine and
// store num/den directly (no atomics, coalesced float4).
__global__ __launch_bounds__(256, 2) void k_attn(
    const u16* __restrict__ pf, const u16* __restrict__ lfb,
    const u16* __restrict__ pfT, const u16* __restrict__ lfT,
    float* __restrict__ pnum, float* __restrict__ pden,
    float* __restrict__ lnum, float* __restrict__ lden){
  int bid = blockIdx.x;
  int pass = (bid < 384);          // heavy (ligand-as-query) blocks first
  int NQ, NK, qt, h;
  const u16 *Q, *Kt, *Vt; float *num, *den;
  if (pass){
    qt = bid >> 3; h = bid & 7;
    NQ = NLIG; NK = NPROT; Q = lfb; Kt = pf; Vt = pfT; num = lnum; den = lden;
  } else {
    int l = bid - 384; qt = l >> 3; h = l & 7;
    NQ = NPROT; NK = NLIG; Q = pf; Kt = lfb; Vt = lfT; num = pnum; den = pden;
  }
  int wv = threadIdx.x>>6, lane = threadIdx.x&63;
  int ql = lane&31, hi = lane>>5;
  int qsub = wv & 1, kvh = wv >> 1;
  int qg = qt*64 + qsub*32 + ql;
  int nt = NK >> 6;                 // tiles of 32 kv per wave (half of NK)
  int kv0 = kvh * (NK >> 1);
  const u16* Qh = Q + (size_t)h*NQ*DD;
  const u16* Kh = Kt + (size_t)h*NK*DD;
  const u16* Vh = Vt + (size_t)h*DD*NK;
  const float SC = 0.125f * 1.44269504088896f;   // log2(e)/sqrt(D)

  // Q as B-operand, pre-scaled by SC: lane(col=q, k=hi*8+j), 4 k16-slices over D=64
  bf8 qf[4];
  #pragma unroll
  for (int kk=0;kk<4;kk++){
    union { bf8 v; u16 s[8]; uint32_t u[4]; } qr, qo;
    qr.v = *(const bf8*)(Qh + (size_t)qg*DD + kk*16 + hi*8);
    #pragma unroll
    for (int j=0;j<4;j++)
      qo.u[j] = cvtpk(bf2f(qr.s[2*j])*SC, bf2f(qr.s[2*j+1])*SC);
    qf[kk] = qo.v;
  }

  f16f o0 = {}, o1 = {};
  float dsum = 0.f;
  const u16* Kp  = Kh + (size_t)(kv0 + ql)*DD + hi*8;
  const u16* Vp0 = Vh + (size_t)ql*NK + kv0 + hi*8;
  const u16* Vp1 = Vh + (size_t)(32+ql)*NK + kv0 + hi*8;

  for (int t=0; t<nt; t++){
    // S^T[kv][q]: A = K rows(kv), B = (Q*SC)^T
    f16f s = {};
    #pragma unroll
    for (int kk=0;kk<4;kk++){
      bf8 kf = *(const bf8*)(Kp + kk*16);
      s = __builtin_amdgcn_mfma_f32_32x32x16_bf16(kf, qf[kk], s, 0, 0, 0);
    }
    // lane(q,hi) holds S^T[kvl=(r&3)+8*(r>>2)+4*hi][q]
    float e[16];
    #pragma unroll
    for (int r=0;r<16;r++){ e[r] = exp2_fast(s[r]); dsum += e[r]; }
    // B-frags for PV: lane(q,hi) needs P[kv = base + hi*8 + j][q]
    union { uint32_t u[4]; bf8 v; } B0, B1;
    {
      u32x2 p;
      p = __builtin_amdgcn_permlane32_swap(cvtpk(e[0],e[1]),   cvtpk(e[4],e[5]),   false, false);
      B0.u[0]=p[0]; B0.u[2]=p[1];
      p = __builtin_amdgcn_permlane32_swap(cvtpk(e[2],e[3]),   cvtpk(e[6],e[7]),   false, false);
      B0.u[1]=p[0]; B0.u[3]=p[1];
      p = __builtin_amdgcn_permlane32_swap(cvtpk(e[8],e[9]),   cvtpk(e[12],e[13]), false, false);
      B1.u[0]=p[0]; B1.u[2]=p[1];
      p = __builtin_amdgcn_permlane32_swap(cvtpk(e[10],e[11]), cvtpk(e[14],e[15]), false, false);
      B1.u[1]=p[0]; B1.u[3]=p[1];
    }
    // O^T[d][q] += V^T[d][kv] * P[kv][q]
    bf8 v00 = *(const bf8*)(Vp0);
    bf8 v01 = *(const bf8*)(Vp0 + 16);
    bf8 v10 = *(const bf8*)(Vp1);
    bf8 v11 = *(const bf8*)(Vp1 + 16);
    o0 = __builtin_amdgcn_mfma_f32_32x32x16_bf16(v00, B0.v, o0, 0, 0, 0);
    o0 = __builtin_amdgcn_mfma_f32_32x32x16_bf16(v01, B1.v, o0, 0, 0, 0);
    o1 = __builtin_amdgcn_mfma_f32_32x32x16_bf16(v10, B0.v, o1, 0, 0, 0);
    o1 = __builtin_amdgcn_mfma_f32_32x32x16_bf16(v11, B1.v, o1, 0, 0, 0);
    Kp += 32*DD; Vp0 += 32; Vp1 += 32;
  }

  // cross-(kv-half) combine via LDS, then direct coalesced stores
  __shared__ float Cmb[2][2][64][16];
  __shared__ float Dls[2][64];
  if (wv >= 2){
    union { f16f v; f4 q[4]; } a0, a1;
    a0.v = o0; a1.v = o1;
    f4* c0 = (f4*)&Cmb[qsub][0][lane][0];
    f4* c1 = (f4*)&Cmb[qsub][1][lane][0];
    #pragma unroll
    for (int r4=0;r4<4;r4++){ c0[r4] = a0.q[r4]; c1[r4] = a1.q[r4]; }
    Dls[qsub][lane] = dsum;
  }
  __syncthreads();
  if (wv < 2){
    f4* c0 = (f4*)&Cmb[qsub][0][lane][0];
    f4* c1 = (f4*)&Cmb[qsub][1][lane][0];
    union { f16f v; f4 q[4]; } b0, b1;
    b0.v = o0; b1.v = o1;
    #pragma unroll
    for (int r4=0;r4<4;r4++){
      f4 t0 = c0[r4], t1 = c1[r4];
      b0.q[r4] += t0; b1.q[r4] += t1;
    }
    dsum += Dls[qsub][lane];
    dsum += __shfl_xor(dsum, 32, 64);
    float* np = num + ((size_t)h*NQ + qg)*DD;
    #pragma unroll
    for (int r4=0;r4<4;r4++){
      *(f4*)(np + r4*8 + 4*hi)      = b0.q[r4];
      *(f4*)(np + 32 + r4*8 + 4*hi) = b1.q[r4];
    }
    if (hi == 0) den[(size_t)h*NQ + qg] = dsum;
  }
}

// ---------------- epilogue: gate * num/den -> LN -> fb -> sigmoid -> pc2/lc2 ----------
__global__ __launch_bounds__(256) void k_post(
    const float* __restrict__ pnum, const float* __restrict__ pden,
    const float* __restrict__ lnum, const float* __restrict__ lden,
    const float* __restrict__ pgate, const float* __restrict__ lgate,
    const float* __restrict__ lnw, const float* __restrict__ lnb,
    const u16* __restrict__ fbT, const float* __restrict__ fbb,
    u16* __restrict__ pc2, u16* __restrict__ lc2){
  int t = blockIdx.x;
  int pass = (t >= NPROT/64);
  int h = blockIdx.y;
  int NQ = pass ? NLIG : NPROT;
  const float* num = pass ? lnum : pnum;
  const float* den = pass ? lden : pden;
  const float* gate = pass ? lgate : pgate;
  u16* oc = pass ? lc2 : pc2;
  int qbase = (pass ? t - NPROT/64 : t) * 64;

  __shared__ u16 Pl[64*72];
  int w = threadIdx.x>>6, lane = threadIdx.x&63;
  int lr = lane&15, lkg = lane>>4, lk = lkg*8;
  u16* Pw = Pl + (w*16)*72;
  int orow0 = qbase + w*16 + lkg*4;

  float rd[4];
  #pragma unroll
  for (int r=0;r<4;r++) rd[r] = 1.f / den[(size_t)h*NQ + orow0 + r];

  float v[4][4];
  #pragma unroll
  for (int cf=0;cf<4;cf++){
    int d = cf*16+lr;
    #pragma unroll
    for (int r=0;r<4;r++)
      v[cf][r] = num[((size_t)h*NQ + orow0 + r)*DD + d] * rd[r]
               * gate[(size_t)(orow0+r)*DD + d];
  }
  float m1[4], m2[4];
  #pragma unroll
  for (int r=0;r<4;r++){
    float s1 = v[0][r]+v[1][r]+v[2][r]+v[3][r];
    float s2 = v[0][r]*v[0][r]+v[1][r]*v[1][r]+v[2][r]*v[2][r]+v[3][r]*v[3][r];
    s1 += __shfl_xor(s1,1,64); s2 += __shfl_xor(s2,1,64);
    s1 += __shfl_xor(s1,2,64); s2 += __shfl_xor(s2,2,64);
    s1 += __shfl_xor(s1,4,64); s2 += __shfl_xor(s2,4,64);
    s1 += __shfl_xor(s1,8,64); s2 += __shfl_xor(s2,8,64);
    float mu = s1 * (1.f/64.f);
    float var = s2 * (1.f/64.f) - mu*mu;
    if (var < 0.f) var = 0.f;
    m1[r] = mu; m2[r] = rsqrtf(var + 1e-5f);
  }
  #pragma unroll
  for (int cf=0;cf<4;cf++){
    int d = cf*16+lr;
    float lw = lnw[d], lb = lnb[d];
    #pragma unroll
    for (int r=0;r<4;r++){
      float n = (v[cf][r]-m1[r])*m2[r]*lw + lb;
      Pw[(lkg*4+r)*72 + d] = f2bf(n);
    }
  }
  f4 z4[4] = {};
  #pragma unroll
  for (int kc=0;kc<2;kc++){
    bf8 pa = *(const bf8*)(Pw + lr*72 + kc*32 + lk);
    #pragma unroll
    for (int cf=0;cf<4;cf++){
      bf8 b = *(const bf8*)(fbT + (size_t)(cf*16+lr)*DD + kc*32 + lk);
      z4[cf] = mfma16(pa, b, z4[cf]);
    }
  }
  #pragma unroll
  for (int cf=0;cf<4;cf++){
    int d = cf*16+lr;
    float bb = fbb[d];
    #pragma unroll
    for (int r=0;r<4;r++){
      float sg = 1.f/(1.f + __expf(-(z4[cf][r] + bb)));
      oc[(size_t)(orow0+r)*F_DIM + h*DD + d] = f2bf(sg);
    }
  }
}

// ---------------- final: out = h (+ cat @ M^T + c for active rows) ----------------
__global__ __launch_bounds__(256) void k_final(const float* __restrict__ hsrc,
    const u16* __restrict__ pc2, const u16* __restrict__ lc2,
    const u16* __restrict__ MpT, const u16* __restrict__ MlT,
    const float* __restrict__ cp, const float* __restrict__ cl,
    float* __restrict__ out){
  int R = blockIdx.x*64;
  int cbase = blockIdx.y*64;
  int tid = threadIdx.x;
  if (R >= NACT){
    int r = tid>>2, s0 = tid&3;
    const float4* hp4 = (const float4*)(hsrc + (size_t)(R+r)*F_DIM + cbase);
    float4* op4 = (float4*)(out + (size_t)(R+r)*F_DIM + cbase);
    #pragma unroll
    for (int s=0;s<4;s++) op4[s0 + s*4] = hp4[s0 + s*4];
    return;
  }
  bool isP = (R < NPROT);
  const u16* A = isP ? (pc2 + (size_t)R*F_DIM) : (lc2 + (size_t)(R-NPROT)*F_DIM);
  const u16* B = isP ? MpT : MlT;
  const float* cv = isP ? cp : cl;
  int w = tid>>6, lane = tid&63, lr = lane&15, lkg = lane>>4, lk = lkg*8;
  const u16* Ap = A + (size_t)(w*16+lr)*F_DIM + lk;
  const u16* Bp = B + (size_t)(cbase+lr)*F_DIM + lk;
  f4 acc[4] = {};
  for (int k=0;k<F_DIM;k+=32){
    bf8 a = *(const bf8*)(Ap+k);
    #pragma unroll
    for (int cf=0;cf<4;cf++){
      bf8 b = *(const bf8*)(Bp + (size_t)cf*16*F_DIM + k);
      acc[cf]=mfma16(a,b,acc[cf]);
    }
  }
  int row0 = R + w*16 + lkg*4;
  #pragma unroll
  for (int cf=0;cf<4;cf++){
    int c = cbase + cf*16 + lr;
    float cc = cv[c];
    #pragma unroll
    for (int r=0;r<4;r++)
      out[(size_t)(row0+r)*F_DIM + c] = acc[cf][r] + cc + hsrc[(size_t)(row0+r)*F_DIM + c];
  }
}

extern "C" void kernel_launch(void* const* d_in, const int* in_sizes, int n_in,
                              void* d_out, int out_size, void* d_ws, size_t ws_size,
                              hipStream_t stream){
  (void)in_sizes; (void)n_in; (void)out_size; (void)ws_size;
  const float* h    = (const float*)d_in[0];
  const float* Wp   = (const float*)d_in[3];
  const float* Wl   = (const float*)d_in[4];
  const float* Upw  = (const float*)d_in[5];
  const float* Upb  = (const float*)d_in[6];
  const float* Ulw  = (const float*)d_in[7];
  const float* Ulb  = (const float*)d_in[8];
  const float* lnw  = (const float*)d_in[9];
  const float* lnb  = (const float*)d_in[10];
  const float* pgw  = (const float*)d_in[11];
  const float* pgb  = (const float*)d_in[12];
  const float* lgw  = (const float*)d_in[13];
  const float* lgb  = (const float*)d_in[14];
  const float* fbw  = (const float*)d_in[15];
  const float* fbb  = (const float*)d_in[16];
  const float* flw  = (const float*)d_in[17];
  const float* flb  = (const float*)d_in[18];
  float* out = (float*)d_out;

  char* wsp = (char*)d_ws;
  size_t off = 0;
  auto alloc = [&](size_t b)->char* {
    char* p = wsp + off; off = (off + b + 255) & ~(size_t)255; return p;
  };
  u16* hb    = (u16*)alloc((size_t)NACT*F_DIM*2);
  u16* WpT   = (u16*)alloc((size_t)NHEAD*DD*F_DIM*2);
  u16* WlT   = (u16*)alloc((size_t)NHEAD*DD*F_DIM*2);
  u16* pgT   = (u16*)alloc((size_t)DD*F_DIM*2);
  u16* lgT   = (u16*)alloc((size_t)DD*F_DIM*2);
  u16* fbT   = (u16*)alloc((size_t)DD*DD*2);
  u16* UpWb  = (u16*)alloc((size_t)NHEAD*DD*F_DIM*2);
  u16* UlWb  = (u16*)alloc((size_t)NHEAD*DD*F_DIM*2);
  u16* flT   = (u16*)alloc((size_t)F_DIM*NHEAD*F_DIM*2);
  u16* pf    = (u16*)alloc((size_t)NHEAD*NPROT*DD*2);
  u16* pfT   = (u16*)alloc((size_t)NHEAD*DD*NPROT*2);
  u16* lfb   = (u16*)alloc((size_t)NHEAD*NLIG*DD*2);
  u16* lfT   = (u16*)alloc((size_t)NHEAD*DD*NLIG*2);
  float* pgate = (float*)alloc((size_t)NPROT*DD*4);
  float* lgate = (float*)alloc((size_t)NLIG*DD*4);
  u16* pc2   = (u16*)alloc((size_t)NPROT*F_DIM*2);
  u16* lc2   = (u16*)alloc((size_t)NLIG*F_DIM*2);
  u16* MpT   = (u16*)alloc((size_t)F_DIM*F_DIM*2);
  u16* MlT   = (u16*)alloc((size_t)F_DIM*F_DIM*2);
  float* cp  = (float*)alloc(F_DIM*4);
  float* cl  = (float*)alloc(F_DIM*4);
  // attention output buffers (fully overwritten by k_attn; no memset needed)
  size_t n_pnum = (size_t)NHEAD*NPROT*DD, n_lnum = (size_t)NHEAD*NLIG*DD;
  size_t n_pden = (size_t)NHEAD*NPROT,     n_lden = (size_t)NHEAD*NLIG;
  float* pnum = (float*)alloc(n_pnum*4);
  float* lnum = (float*)alloc(n_lnum*4);
  float* pden = (float*)alloc(n_pden*4);
  float* lden = (float*)alloc(n_lden*4);

  // prep: bf16 conversions / transposes
  k_cvt<<<dim3((NACT*F_DIM/4 + 255)/256), 256, 0, stream>>>(h, hb, NACT*F_DIM/4);
  k_cvt<<<dim3((NHEAD*DD*F_DIM/4 + 255)/256), 256, 0, stream>>>(Upw, UpWb, NHEAD*DD*F_DIM/4);
  k_cvt<<<dim3((NHEAD*DD*F_DIM/4 + 255)/256), 256, 0, stream>>>(Ulw, UlWb, NHEAD*DD*F_DIM/4);
  k_cvtT64<<<dim3(1, 8, NHEAD), 256, 0, stream>>>(Wp, WpT, F_DIM, DD);
  k_cvtT64<<<dim3(1, 8, NHEAD), 256, 0, stream>>>(Wl, WlT, F_DIM, DD);
  k_cvtT64<<<dim3(1, 8, 1), 256, 0, stream>>>(pgw, pgT, F_DIM, DD);
  k_cvtT64<<<dim3(1, 8, 1), 256, 0, stream>>>(lgw, lgT, F_DIM, DD);
  k_cvtT64<<<dim3(1, 1, 1), 256, 0, stream>>>(fbw, fbT, DD, DD);
  k_cvtT64<<<dim3(8, 64, 1), 256, 0, stream>>>(flw, flT, NHEAD*F_DIM, F_DIM);

  // projections, gates, folded output matrices
  k_proj<<<dim3(NPROT/64, NHEAD, 2), 256, 0, stream>>>(hb, WpT, WlT, pf, pfT, lfb, lfT);
  k_gate<<<dim3(NPROT/64, 1, 2), 256, 0, stream>>>(hb, pgT, lgT, pgb, lgb, pgate, lgate);
  k_mw<<<dim3(F_DIM/64, NHEAD, 2), 256, 0, stream>>>(UpWb, UlWb, flT, MpT, MlT);
  k_cinit<<<dim3(2), 256, 0, stream>>>(flb, cp, cl);
  k_cacc<<<dim3(32, 2, 2), 256, 0, stream>>>(flw, Upb, Ulb, cp, cl);

  // co-attention: block-owned outputs, no atomics
  k_attn<<<dim3(1152), 256, 0, stream>>>(pf, lfb, pfT, lfT, pnum, pden, lnum, lden);
  // epilogue
  k_post<<<dim3(NPROT/64 + NLIG/64, NHEAD), 256, 0, stream>>>(
      pnum, pden, lnum, lden, pgate, lgate, lnw, lnb, fbT, fbb, pc2, lc2);
  // final projection + residual + passthrough
  k_final<<<dim3(NTOT/64, F_DIM/64), 256, 0, stream>>>(h, pc2, lc2, MpT, MlT, cp, cl, out);
}